// Round 7
// baseline (1213.888 us; speedup 1.0000x reference)
//
#include <hip/hip_runtime.h>
#include <cstdint>
#include <cmath>

// ---------------------------------------------------------------------------
// HawkBlock on MI355X (gfx950). Round 11.
// R10 (1122 us, best): gemm2 at 961 TF = above the m97 ceiling; MfmaUtil 44 +
// VALUBusy 42 = saturated 128^2 structure. R11: faithful m201 8-phase port on
// the THREE dual-B GEMM dispatches only (z-GEMM + ADDF gemm1s unchanged as
// within-run control). Differences vs failed R5-R7: ONE half-tile stage per
// phase (even interleave, m196's lever), stage rotation derived from region
// lifetimes with >=1 post-MFMA barrier separation (race-free by barrier
// semantics, no timing assumptions), VMC(4) at ph4/ph8 only with per-iteration
// epilogue degradation to VMC(0).
//   region last read: Bl ph1, Bh ph2, Al/Ah ph3 (wave wm-half at ph1+ph3)
//   stages: ph1 (t+1).Bh | ph2 (t+1).Ah | ph3 (t+2).Bl | ph4 (t+2).Al+VMC
//           ph5 (t+2).Bh | ph6 (t+2).Ah | ph7 (t+3).Bl | ph8 (t+3).Al+VMC
//   ph4 VMC(4): 12 outstanding -> drains all of t+1 (read ph5-8)
//   ph8 VMC(4): 12 outstanding -> drains all of t+2 (read next ph1-4)
// ---------------------------------------------------------------------------

typedef unsigned short u16;
typedef _Float16 f16;
typedef __bf16 bf16x8 __attribute__((ext_vector_type(8)));
typedef float  f32x4  __attribute__((ext_vector_type(4)));

#define BM 128
#define BN 128
#define BK 64

#define HID   1024
#define DREC  2048
#define INTER 4096
#define BT    16384   // B*T rows
#define TLEN  4096
#define NCHAN 8192    // B * DREC
#define CHUNK 64
#define NCH   64      // TLEN / CHUNK
#define NPAIR 4096    // NCHAN/2 channel pairs

__device__ __forceinline__ float b2f(u16 u) {
  union { unsigned int i; float f; } v; v.i = ((unsigned int)u) << 16; return v.f;
}
__device__ __forceinline__ u16 f2bf(float f) {  // RNE
  unsigned int u = __builtin_bit_cast(unsigned int, f);
  u += 0x7FFFu + ((u >> 16) & 1u);
  return (u16)(u >> 16);
}
__device__ __forceinline__ float sigm(float x) { return 1.f / (1.f + expf(-x)); }

typedef __attribute__((address_space(1))) void as1_void;
typedef __attribute__((address_space(3))) void as3_void;
__device__ __forceinline__ void async16(const void* g, void* l) {
  __builtin_amdgcn_global_load_lds((as1_void*)g, (as3_void*)l, 16, 0, 0);
}

#define BARSYNC() do { __builtin_amdgcn_s_barrier(); __builtin_amdgcn_sched_barrier(0); } while (0)
#define LGKM0()   do { asm volatile("s_waitcnt lgkmcnt(0)" ::: "memory"); __builtin_amdgcn_sched_barrier(0); } while (0)
#define LGKM8()   do { asm volatile("s_waitcnt lgkmcnt(8)" ::: "memory"); } while (0)
#define VMC(N)    do { asm volatile("s_waitcnt vmcnt(" #N ")" ::: "memory"); __builtin_amdgcn_sched_barrier(0); } while (0)
#define FENCE()   do { asm volatile("" ::: "memory"); __builtin_amdgcn_sched_barrier(0); } while (0)

// XCD-aware remap (T1), used by gemm1 only (measured: helps gemm1, hurts gemm2).
__device__ __forceinline__ void xcd_remap(int& bx, int& by) {
  const int gx = gridDim.x, gy = gridDim.y;
  const int nwg = gx * gy;
  const int lid = blockIdx.x + gx * blockIdx.y;
  const int rid = (lid & 7) * (nwg >> 3) + (lid >> 3);   // XCD-contiguous
  bx = rid / gy;
  by = rid - bx * gy;
}

// ---------------------------------------------------------------------------
// All 7 weight conversions in ONE kernel (unchanged).
__global__ void f2b_all(const float* s0, const float* s1, const float* s2,
                        const float* s3, const float* s4, const float* s5,
                        const float* s6,
                        u16* d0, u16* d1, u16* d2, u16* d3, u16* d4, u16* d5,
                        u16* d6) {
  int blk = blockIdx.x;
  const float* src; u16* dst; int rel;
  if      (blk < 2048)  { src = s0; dst = d0; rel = blk; }
  else if (blk < 4096)  { src = s1; dst = d1; rel = blk - 2048; }
  else if (blk < 8192)  { src = s2; dst = d2; rel = blk - 4096; }
  else if (blk < 10240) { src = s3; dst = d3; rel = blk - 8192; }
  else if (blk < 14336) { src = s4; dst = d4; rel = blk - 10240; }
  else if (blk < 18432) { src = s5; dst = d5; rel = blk - 14336; }
  else                  { src = s6; dst = d6; rel = blk - 18432; }
  int i = rel * 256 + threadIdx.x;
  float4 v = ((const float4*)src)[i];
  ushort4 o;
  o.x = f2bf(v.x); o.y = f2bf(v.y); o.z = f2bf(v.z); o.w = f2bf(v.w);
  ((ushort4*)dst)[i] = o;
}

// rmsnorm over rows of 1024 fp32, bf16 out (unchanged).
__global__ void rmsnorm_kernel(const float* __restrict__ x, const float* __restrict__ w,
                               u16* __restrict__ out) {
  const int row = blockIdx.x;
  const int tid = threadIdx.x;
  float4 v = ((const float4*)(x + (size_t)row * HID))[tid];
  float ss = v.x * v.x + v.y * v.y + v.z * v.z + v.w * v.w;
#pragma unroll
  for (int o = 32; o > 0; o >>= 1) ss += __shfl_down(ss, o);
  __shared__ float red[4];
  const int lane = tid & 63, wv = tid >> 6;
  if (lane == 0) red[wv] = ss;
  __syncthreads();
  float tot = red[0] + red[1] + red[2] + red[3];
  float sc = rsqrtf(tot * (1.f / (float)HID) + 1e-6f);
  float4 wv4 = ((const float4*)w)[tid];
  ushort4 o;
  o.x = f2bf(v.x * sc * wv4.x); o.y = f2bf(v.y * sc * wv4.y);
  o.z = f2bf(v.z * sc * wv4.z); o.w = f2bf(v.w * sc * wv4.w);
  ((ushort4*)(out + (size_t)row * HID))[tid] = o;
}

// ---------------------------------------------------------------------------
// Shared GEMM building blocks. Chunk-XOR swizzle on the pre-swizzled GLOBAL
// source (0 bank conflicts measured R4-R10); LDS dest linear.
__device__ __forceinline__ void stageG(const u16* __restrict__ g, int ldg,
                                       int rb, int k0, u16* lbase, int tid,
                                       int nthr) {
#pragma unroll
  for (int i = 0; i < 2; ++i) {
    int p = i * nthr + tid;         // 16B-chunk index
    int r = p >> 3;                 // local row
    int sg = (p & 7) ^ (r & 7);     // swizzled source chunk
    async16(g + (size_t)(rb + r) * ldg + (k0 + sg * 8), (char*)lbase + p * 16);
  }
}

__device__ __forceinline__ void readA4(bf16x8 (&af)[4][2], const u16* base,
                                       int rbase, int quad) {
#pragma unroll
  for (int i = 0; i < 4; ++i) {
    int r = rbase + i * 16;
#pragma unroll
    for (int ks = 0; ks < 2; ++ks)
      af[i][ks] = ((const bf16x8*)base)[r * 8 + ((ks * 4 + quad) ^ (r & 7))];
  }
}
__device__ __forceinline__ void readB2(bf16x8 (&bf)[2][2], const u16* base,
                                       int rbase, int quad) {
#pragma unroll
  for (int i = 0; i < 2; ++i) {
    int r = rbase + i * 16;
#pragma unroll
    for (int ks = 0; ks < 2; ++ks)
      bf[i][ks] = ((const bf16x8*)base)[r * 8 + ((ks * 4 + quad) ^ (r & 7))];
  }
}

template <int MI0, int NI0, int NA>
__device__ __forceinline__ void mfmaQ(f32x4 (&acc)[8][NA],
                                      const bf16x8 (&af)[4][2],
                                      const bf16x8 (&bf)[2][2]) {
  __builtin_amdgcn_s_setprio(1);
#pragma unroll
  for (int mi = 0; mi < 4; ++mi)
#pragma unroll
    for (int ni = 0; ni < 2; ++ni)
#pragma unroll
      for (int ks = 0; ks < 2; ++ks)
        acc[MI0 + mi][NI0 + ni] = __builtin_amdgcn_mfma_f32_16x16x32_bf16(
            af[mi][ks], bf[ni][ks], acc[MI0 + mi][NI0 + ni], 0, 0, 0);
  __builtin_amdgcn_s_setprio(0);
}

// ---------------------------------------------------------------------------
// Single-B GEMM (z-GEMM + ADDF), R10-proven 128^2 structure, remap + lb(256,4).
enum { EPI_LOGIT = 0, EPI_ADDF = 1 };

template <int EPI>
__global__ __launch_bounds__(256, 4)
void gemm1(const u16* __restrict__ A, const u16* __restrict__ W,
           int K, int N, int ldA, int ldW,
           float* outf, f16* outz, const float* auxf) {
  __shared__ alignas(16) u16 sA[BM * BK];
  __shared__ alignas(16) u16 sB[BN * BK];

  const int tid  = threadIdx.x;
  const int lane = tid & 63;
  const int wv   = tid >> 6;
  const int wm   = wv & 1;
  const int wn   = wv >> 1;
  const int lm   = lane & 15;
  const int quad = lane >> 4;

  int bx, by;
  xcd_remap(bx, by);
  const int row0 = bx * BM;
  const int col0 = by * BN;

  f32x4 acc[4][4];
#pragma unroll
  for (int i = 0; i < 4; ++i)
#pragma unroll
    for (int j = 0; j < 4; ++j) acc[i][j] = (f32x4)0.f;

  for (int k0 = 0; k0 < K; k0 += BK) {
#pragma unroll
    for (int i = 0; i < 4; ++i) {
      int p = i * 256 + tid;
      int r = p >> 3;
      int sg = (p & 7) ^ (r & 7);
      async16(A + (size_t)(row0 + r) * ldA + (k0 + sg * 8), (char*)sA + p * 16);
    }
#pragma unroll
    for (int i = 0; i < 4; ++i) {
      int p = i * 256 + tid;
      int r = p >> 3;
      int sg = (p & 7) ^ (r & 7);
      async16(W + (size_t)(col0 + r) * ldW + (k0 + sg * 8), (char*)sB + p * 16);
    }
    __syncthreads();

#pragma unroll
    for (int h = 0; h < 2; ++h) {
      bf16x8 af[4], bf[4];
#pragma unroll
      for (int mi = 0; mi < 4; ++mi) {
        int r = wm * 64 + mi * 16 + lm;
        af[mi] = ((const bf16x8*)sA)[r * 8 + ((h * 4 + quad) ^ (r & 7))];
      }
#pragma unroll
      for (int ni = 0; ni < 4; ++ni) {
        int c = wn * 64 + ni * 16 + lm;
        bf[ni] = ((const bf16x8*)sB)[c * 8 + ((h * 4 + quad) ^ (c & 7))];
      }
#pragma unroll
      for (int mi = 0; mi < 4; ++mi)
#pragma unroll
        for (int ni = 0; ni < 4; ++ni)
          acc[mi][ni] = __builtin_amdgcn_mfma_f32_16x16x32_bf16(af[mi], bf[ni], acc[mi][ni], 0, 0, 0);
    }
    __syncthreads();
  }

#pragma unroll
  for (int mi = 0; mi < 4; ++mi) {
    const int rbase = row0 + wm * 64 + mi * 16 + quad * 4;
#pragma unroll
    for (int ni = 0; ni < 4; ++ni) {
      const int cg = col0 + wn * 64 + ni * 16 + lm;
      f32x4 v = acc[mi][ni];
#pragma unroll
      for (int rr = 0; rr < 4; ++rr) {
        size_t idx = (size_t)(rbase + rr) * N + cg;
        float t = v[rr];
        if constexpr (EPI == EPI_LOGIT) {
          outz[idx] = (f16)(t + auxf[cg]);      // pre-sigmoid logit, fp16
        } else {
          outf[idx] = t + auxf[idx];            // residual add; auxf may == outf
        }
      }
    }
  }
}

// ---------------------------------------------------------------------------
// Dual-B 8-phase GEMM: block 256 rows x 128 cols PER MATRIX, 512 threads
// (8 waves, 2Mx4N; wave tile 128x32 per matrix), LDS 128KB double-buffered.
// Schedule per header comment. Tiles: even->buf0, odd->buf1 (static indices).
enum { EPI2_XG = 0, EPI2_SM = 1 };

template <int EPI>
__global__ __launch_bounds__(512, 2)
void gemm2p8(const u16* __restrict__ A, const u16* __restrict__ W0,
             const u16* __restrict__ W1,
             int K, int N, int ldA, int ldW,
             u16* out0, u16* out1) {
  __shared__ u16 sA[2][16384];   // [buf][Al rows 0-127 | Ah rows 128-255]
  __shared__ u16 sB[2][16384];   // [buf][Bl = matrix0 128x64 | Bh = matrix1]
  const int tid  = threadIdx.x;
  const int lane = tid & 63, wv = tid >> 6;
  const int wm   = wv >> 2, wn = wv & 3;
  const int lm   = lane & 15, quad = lane >> 4;
  const int row0 = blockIdx.x * 256, col0 = blockIdx.y * 128;
  const int NT   = K >> 6, NI = NT >> 1;

  f32x4 acc0[8][2], acc1[8][2];
#pragma unroll
  for (int i = 0; i < 8; ++i)
#pragma unroll
    for (int j = 0; j < 2; ++j) { acc0[i][j] = (f32x4)0.f; acc1[i][j] = (f32x4)0.f; }

  // Prologue: t0 fully (8 loads) + t1.{Bl,Al} (4); VMC(4) drains t0 exactly;
  // in-flight = t1.{Bl,Al} == loop steady state.
  stageG(W0, ldW, col0,       0, sB[0],        tid, 512);  // t0.Bl
  stageG(A,  ldA, row0,       0, sA[0],        tid, 512);  // t0.Al
  stageG(W1, ldW, col0,       0, sB[0] + 8192, tid, 512);  // t0.Bh
  stageG(A,  ldA, row0 + 128, 0, sA[0] + 8192, tid, 512);  // t0.Ah
  FENCE();
  stageG(W0, ldW, col0, 64, sB[1], tid, 512);              // t1.Bl
  stageG(A,  ldA, row0, 64, sA[1], tid, 512);              // t1.Al
  VMC(4);
  BARSYNC();

  for (int j = 0; j < NI; ++j) {
    const int t  = j << 1;
    const int k1 = (t + 1) * 64, k2 = (t + 2) * 64, k3 = (t + 3) * 64;
    const bool s2 = (t + 2 < NT), s3 = (t + 3 < NT);
    bf16x8 afL[4][2], afH[4][2], bf0[2][2], bf1[2][2];

    // ======== tile t (buf0), phases 1-4 ========
    // ph1: Q acc0-lo (afL x bf0); stage (t+1).Bh
    readA4(afL, sA[0], wm * 128 + lm, quad);
    readB2(bf0, sB[0], wn * 32 + lm, quad);
    stageG(W1, ldW, col0, k1, sB[1] + 8192, tid, 512);
    LGKM8();
    BARSYNC(); LGKM0();
    mfmaQ<0, 0>(acc0, afL, bf0);
    BARSYNC();

    // ph2: Q acc1-lo (afL x bf1); stage (t+1).Ah
    readB2(bf1, sB[0] + 8192, wn * 32 + lm, quad);
    stageG(A, ldA, row0 + 128, k1, sA[1] + 8192, tid, 512);
    BARSYNC(); LGKM0();
    mfmaQ<0, 0>(acc1, afL, bf1);
    BARSYNC();

    // ph3: Q acc1-hi (afH x bf1); stage (t+2).Bl  [Bl free after ph1]
    readA4(afH, sA[0], wm * 128 + 64 + lm, quad);
    if (s2) stageG(W0, ldW, col0, k2, sB[0], tid, 512);
    BARSYNC(); LGKM0();
    mfmaQ<4, 0>(acc1, afH, bf1);
    BARSYNC();

    // ph4: Q acc0-hi (afH x bf0); stage (t+2).Al  [Al free after ph3]
    if (s2) { stageG(A, ldA, row0, k2, sA[0], tid, 512); VMC(4); }
    else    { VMC(0); }
    BARSYNC();
    mfmaQ<4, 0>(acc0, afH, bf0);
    BARSYNC();

    // ======== tile t+1 (buf1), phases 5-8 ========
    // ph5: stage (t+2).Bh  [buf0.Bh free after ph2]
    readA4(afL, sA[1], wm * 128 + lm, quad);
    readB2(bf0, sB[1], wn * 32 + lm, quad);
    if (s2) stageG(W1, ldW, col0, k2, sB[0] + 8192, tid, 512);
    LGKM8();
    BARSYNC(); LGKM0();
    mfmaQ<0, 0>(acc0, afL, bf0);
    BARSYNC();

    // ph6: stage (t+2).Ah  [buf0.Ah free after ph3]
    readB2(bf1, sB[1] + 8192, wn * 32 + lm, quad);
    if (s2) stageG(A, ldA, row0 + 128, k2, sA[0] + 8192, tid, 512);
    BARSYNC(); LGKM0();
    mfmaQ<0, 0>(acc1, afL, bf1);
    BARSYNC();

    // ph7: stage (t+3).Bl  [buf1.Bl free after ph5]
    readA4(afH, sA[1], wm * 128 + 64 + lm, quad);
    if (s3) stageG(W0, ldW, col0, k3, sB[1], tid, 512);
    BARSYNC(); LGKM0();
    mfmaQ<4, 0>(acc1, afH, bf1);
    BARSYNC();

    // ph8: stage (t+3).Al  [buf1.Al free after ph7]; drain t+2
    if (s3) { stageG(A, ldA, row0, k3, sA[1], tid, 512); VMC(4); }
    else if (s2) { VMC(0); }
    else { VMC(0); }
    BARSYNC();
    mfmaQ<4, 0>(acc0, afH, bf0);
    BARSYNC();
  }

  // Epilogue. C/D layout: col = lane&15, row = quad*4 + reg (m89/m91).
#pragma unroll
  for (int mi = 0; mi < 8; ++mi) {
    const int rb = row0 + wm * 128 + mi * 16 + quad * 4;
#pragma unroll
    for (int ni = 0; ni < 2; ++ni) {
      const int cg = col0 + wn * 32 + ni * 16 + lm;
#pragma unroll
      for (int rr = 0; rr < 4; ++rr) {
        size_t idx = (size_t)(rb + rr) * N + cg;
        float v0 = acc0[mi][ni][rr];
        float v1 = acc1[mi][ni][rr];
        if constexpr (EPI == EPI2_XG) {
          out0[idx] = f2bf(v0);                 // xin raw
          out1[idx] = f2bf(sigm(v1));           // gate
        } else {
          out0[idx] = f2bf(v0 * sigm(v0) * v1); // m = silu(g) * u
        }
      }
    }
  }
}

// ---------------------------------------------------------------------------
// Chunked scan (unchanged).
__global__ void scan_phase1(const f16* __restrict__ z, const u16* __restrict__ xin,
                            float2* __restrict__ ch_h, float2* __restrict__ ch_p) {
  int gtid = blockIdx.x * 256 + threadIdx.x;
  int c = gtid >> 12;
  int pair = gtid & (NPAIR - 1);
  int b = pair >> 10;
  int d = (pair & 1023) * 2;
  size_t base = ((size_t)b * TLEN + (size_t)c * CHUNK) * DREC + d;
  float2 h = {0.f, 0.f}, P = {1.f, 1.f};
#pragma unroll 8
  for (int t = 0; t < CHUNK; ++t) {
    size_t i = base + (size_t)t * DREC;
    f16 z2[2]; *(uint32_t*)z2 = *(const uint32_t*)(z + i);
    u16 x2[2]; *(uint32_t*)x2 = *(const uint32_t*)(xin + i);
    float a0 = sigm((float)z2[0]), a1 = sigm((float)z2[1]);
    h.x = a0 * h.x + sqrtf(1.f - a0 * a0 + 1e-8f) * b2f(x2[0]);
    h.y = a1 * h.y + sqrtf(1.f - a1 * a1 + 1e-8f) * b2f(x2[1]);
    P.x *= a0; P.y *= a1;
  }
  ch_h[gtid] = h;
  ch_p[gtid] = P;
}

__global__ void scan_phase2(float2* __restrict__ ch_h, const float2* __restrict__ ch_p) {
  int pair = blockIdx.x * 256 + threadIdx.x;
  float2 H = {0.f, 0.f};
#pragma unroll
  for (int c = 0; c < NCH; ++c) {
    int i = c * NPAIR + pair;
    float2 he = ch_h[i];
    float2 P  = ch_p[i];
    ch_h[i] = H;
    H.x = he.x + P.x * H.x;
    H.y = he.y + P.y * H.y;
  }
}

__global__ void scan_phase3(const f16* __restrict__ z, const u16* __restrict__ xin,
                            u16* gate_y, const float2* __restrict__ ch_h) {
  int gtid = blockIdx.x * 256 + threadIdx.x;
  int c = gtid >> 12;
  int pair = gtid & (NPAIR - 1);
  int b = pair >> 10;
  int d = (pair & 1023) * 2;
  size_t base = ((size_t)b * TLEN + (size_t)c * CHUNK) * DREC + d;
  float2 h = ch_h[gtid];
#pragma unroll 8
  for (int t = 0; t < CHUNK; ++t) {
    size_t i = base + (size_t)t * DREC;
    f16 z2[2]; *(uint32_t*)z2 = *(const uint32_t*)(z + i);
    u16 x2[2]; *(uint32_t*)x2 = *(const uint32_t*)(xin + i);
    u16 g2[2]; *(uint32_t*)g2 = *(const uint32_t*)(gate_y + i);
    float a0 = sigm((float)z2[0]), a1 = sigm((float)z2[1]);
    h.x = a0 * h.x + sqrtf(1.f - a0 * a0 + 1e-8f) * b2f(x2[0]);
    h.y = a1 * h.y + sqrtf(1.f - a1 * a1 + 1e-8f) * b2f(x2[1]);
    u16 o2[2];
    o2[0] = f2bf(b2f(g2[0]) * h.x);
    o2[1] = f2bf(b2f(g2[1]) * h.y);
    *(uint32_t*)(gate_y + i) = *(uint32_t*)o2;
  }
}

// ---------------------------------------------------------------------------
extern "C" void kernel_launch(void* const* d_in, const int* in_sizes, int n_in,
                              void* d_out, int out_size, void* d_ws, size_t ws_size,
                              hipStream_t stream) {
  const float* x      = (const float*)d_in[0];
  const float* ln1    = (const float*)d_in[1];
  const float* ln2    = (const float*)d_in[2];
  const float* w_in   = (const float*)d_in[3];
  const float* w_gate = (const float*)d_in[4];
  const float* a_par  = (const float*)d_in[5];
  const float* w_a    = (const float*)d_in[6];
  const float* w_out  = (const float*)d_in[7];
  const float* w_mg   = (const float*)d_in[8];
  const float* w_mu   = (const float*)d_in[9];
  const float* w_md   = (const float*)d_in[10];
  float* out = (float*)d_out;
  char* ws = (char*)d_ws;

  const size_t MB = 1024ull * 1024ull;
  u16* wb_in  = (u16*)(ws + 0 * MB);
  u16* wb_gt  = (u16*)(ws + 4 * MB);
  u16* wb_a   = (u16*)(ws + 8 * MB);
  u16* wb_out = (u16*)(ws + 16 * MB);
  u16* wb_mg  = (u16*)(ws + 20 * MB);
  u16* wb_mu  = (u16*)(ws + 28 * MB);
  u16* wb_md  = (u16*)(ws + 36 * MB);
  u16* hbuf  = (u16*)(ws + 44 * MB);
  f16* zbuf  = (f16*)(ws + 44 * MB);
  u16* gateb = (u16*)(ws + 108 * MB);
  u16* mbuf  = (u16*)(ws + 108 * MB);
  float2* chh = (float2*)(ws + 0 * MB);
  float2* chp = (float2*)(ws + 2 * MB);
  u16* xinb = (u16*)d_out;

  // 1) all weights -> bf16
  f2b_all<<<22528, 256, 0, stream>>>(w_in, w_gate, w_a, w_out, w_mg, w_mu, w_md,
                                     wb_in, wb_gt, wb_a, wb_out, wb_mg, wb_mu, wb_md);

  // 2) h = rmsnorm(x, ln1)
  rmsnorm_kernel<<<BT, 256, 0, stream>>>(x, ln1, hbuf);

  // 3) fused: xin = h@w_in^T (raw -> d_out), gate = sigmoid(h@w_gate^T)
  gemm2p8<EPI2_XG><<<dim3(BT / 256, DREC / 128), 512, 0, stream>>>(
      hbuf, wb_in, wb_gt, HID, DREC, HID, HID, xinb, gateb);

  // 4) z = a_param + xin@w_a^T  (fp16 logits)
  gemm1<EPI_LOGIT><<<dim3(BT / BM, DREC / BN), 256, 0, stream>>>(
      xinb, wb_a, DREC, DREC, DREC, DREC, nullptr, zbuf, a_par);

  // 5) chunked scan; y = gate*h in place over gate
  scan_phase1<<<NCH * NPAIR / 256, 256, 0, stream>>>(zbuf, xinb, chh, chp);
  scan_phase2<<<NPAIR / 256, 256, 0, stream>>>(chh, chp);
  scan_phase3<<<NCH * NPAIR / 256, 256, 0, stream>>>(zbuf, xinb, gateb, chh);

  // 6) xr = x + y@w_out^T  -> d_out (xin dead)
  gemm1<EPI_ADDF><<<dim3(BT / BM, HID / BN), 256, 0, stream>>>(
      gateb, wb_out, DREC, HID, DREC, DREC, out, nullptr, x);

  // 7) h2 = rmsnorm(xr, ln2)
  rmsnorm_kernel<<<BT, 256, 0, stream>>>(out, ln2, hbuf);

  // 8) MLP in two INTER halves; down-GEMM accumulates into d_out in place
  for (int half = 0; half < 2; ++half) {
    const u16* wmg_h = wb_mg + (size_t)half * 2048 * HID;
    const u16* wmu_h = wb_mu + (size_t)half * 2048 * HID;
    const u16* wmd_h = wb_md + (size_t)half * 2048;      // column slice, ldW=INTER
    gemm2p8<EPI2_SM><<<dim3(BT / 256, 2048 / 128), 512, 0, stream>>>(
        hbuf, wmg_h, wmu_h, HID, 2048, HID, HID, mbuf, nullptr);
    gemm1<EPI_ADDF><<<dim3(BT / BM, HID / BN), 256, 0, stream>>>(
        mbuf, wmd_h, 2048, HID, 2048, INTER, out, nullptr, out);
  }
}